// Round 7
// baseline (889.868 us; speedup 1.0000x reference)
//
#include <hip/hip_runtime.h>
#include <hip/hip_bf16.h>
#include <math.h>

#define NTOK 32768
#define DD   1024
#define HH   2048
#define EE   8

#define BM 256
#define BN 256
#define BK 64
#define MAXT2 144  // max 256-row tiles: 128 + 7 worst-case, padded
#define NBLK 128   // NTOK / 256

typedef __bf16 bf16x8 __attribute__((ext_vector_type(8)));
typedef __bf16 bf16x4 __attribute__((ext_vector_type(4)));
typedef float  f32x4  __attribute__((ext_vector_type(4)));

__device__ __forceinline__ void gload_lds16(const void* g, void* l) {
  __builtin_amdgcn_global_load_lds((__attribute__((address_space(1))) void*)(g),
                                   (__attribute__((address_space(3))) void*)(l),
                                   16, 0, 0);
}

__device__ __forceinline__ float fast_gelu(float v) {
  // exact-GELU via A&S 7.1.26 erf (|err| <= 1.5e-7), ~15 VALU + 1 exp
  float az = fabsf(v) * 0.70710678118654752f;
  float t = 1.0f / (1.0f + 0.3275911f * az);
  float poly = t * (0.254829592f + t * (-0.284496736f +
               t * (1.421413741f + t * (-1.453152027f + t * 1.061405429f))));
  float erfa = 1.0f - poly * __expf(-az * az);
  float s = copysignf(erfa, v);
  return 0.5f * v * (1.0f + s);
}

// ---------------- gating + fused x->bf16 cast ----------------
__global__ __launch_bounds__(256) void k_gating(
    const float* __restrict__ x, const float* __restrict__ wg,
    const float* __restrict__ bg, int* __restrict__ eid,
    float* __restrict__ coef, __bf16* __restrict__ xbf)
{
  int lane = threadIdx.x & 63;
  int wave = threadIdx.x >> 6;
  int t0 = blockIdx.x * 8 + wave * 2;

  const float* xr0 = x + (size_t)t0 * DD;
  const float* xr1 = x + (size_t)(t0 + 1) * DD;
  double s0[8] = {}, s1[8] = {};
#pragma unroll
  for (int it = 0; it < 4; ++it) {
    int c0 = it * 256 + lane * 4;
    float4 xa = *(const float4*)(xr0 + c0);
    float4 xb = *(const float4*)(xr1 + c0);
    bf16x4 ca, cb;
#pragma unroll
    for (int j = 0; j < 4; ++j) { ca[j] = (__bf16)(&xa.x)[j]; cb[j] = (__bf16)(&xb.x)[j]; }
    *(bf16x4*)(xbf + (size_t)t0 * DD + c0) = ca;
    *(bf16x4*)(xbf + (size_t)(t0 + 1) * DD + c0) = cb;
    const float* w = wg + (size_t)c0 * EE;
#pragma unroll
    for (int j = 0; j < 4; ++j) {
      double fa = (double)(&xa.x)[j];
      double fb = (double)(&xb.x)[j];
#pragma unroll
      for (int e2 = 0; e2 < 8; ++e2) {
        double wv = (double)w[j * EE + e2];
        s0[e2] += fa * wv;
        s1[e2] += fb * wv;
      }
    }
  }

  int sel = lane & 1, sel2 = (lane >> 1) & 1, sel3 = (lane >> 2) & 1;
  int e = (lane & 1) * 4 + (lane & 2) + ((lane >> 2) & 1);
  double bge = (double)bg[e];

#pragma unroll
  for (int tk = 0; tk < 2; ++tk) {
    double* s = tk ? s1 : s0;
    double v4[4];
#pragma unroll
    for (int j = 0; j < 4; ++j) {
      double keep = sel ? s[4 + j] : s[j];
      double send = sel ? s[j] : s[4 + j];
      v4[j] = keep + __shfl_xor(send, 1, 64);
    }
    double v2[2];
#pragma unroll
    for (int j = 0; j < 2; ++j) {
      double keep = sel2 ? v4[2 + j] : v4[j];
      double send = sel2 ? v4[j] : v4[2 + j];
      v2[j] = keep + __shfl_xor(send, 2, 64);
    }
    double keep = sel3 ? v2[1] : v2[0];
    double send = sel3 ? v2[0] : v2[1];
    double tt = keep + __shfl_xor(send, 4, 64);
    tt += __shfl_xor(tt, 8, 64);
    tt += __shfl_xor(tt, 16, 64);
    tt += __shfl_xor(tt, 32, 64);
    double logit = tt + bge;
    double ml = logit; int me = e;
#pragma unroll
    for (int d2 = 1; d2 < 8; d2 <<= 1) {
      double ol = __shfl_xor(ml, d2, 64);
      int oe = __shfl_xor(me, d2, 64);
      if (ol > ml || (ol == ml && oe < me)) { ml = ol; me = oe; }
    }
    double se = exp(logit - ml);
#pragma unroll
    for (int d2 = 1; d2 < 8; d2 <<= 1) se += __shfl_xor(se, d2, 64);
    if (lane == 0) {
      eid[t0 + tk] = me;
      coef[t0 + tk] = (float)(1.0 / se);
    }
  }
}

// ---------------- per-block histogram (LDS atomics only) ----------------
__global__ __launch_bounds__(256) void k_hist(const int* __restrict__ eid,
                                              int* __restrict__ bhist) {
  __shared__ int h[EE];
  if (threadIdx.x < EE) h[threadIdx.x] = 0;
  __syncthreads();
  int t = blockIdx.x * 256 + threadIdx.x;
  atomicAdd(&h[eid[t]], 1);
  __syncthreads();
  if (threadIdx.x < EE) bhist[blockIdx.x * EE + threadIdx.x] = h[threadIdx.x];
}

// ---------------- scan: offs, per-block bases, 256-tile table ----------------
__global__ void k_scan(const int* __restrict__ bhist, int* __restrict__ offs,
                       int* __restrict__ bbase, int2* __restrict__ tiles) {
  __shared__ int counts_s[EE];
  __shared__ int offs_s[EE + 1];
  int lane = threadIdx.x;
  if (lane < EE) {
    int sum = 0;
    for (int b = 0; b < NBLK; ++b) sum += bhist[b * EE + lane];
    counts_s[lane] = sum;
  }
  __syncthreads();
  if (lane == 0) {
    int a = 0;
    for (int e = 0; e < EE; ++e) { offs_s[e] = a; offs[e] = a; a += counts_s[e]; }
    offs_s[EE] = a; offs[EE] = a;
    int nt = 0;
    for (int e = 0; e < EE; ++e)
      for (int mt = 0; mt * BM < counts_s[e]; ++mt) tiles[nt++] = make_int2(e, mt);
    for (; nt < MAXT2; ++nt) tiles[nt] = make_int2(-1, 0);
  }
  __syncthreads();
  if (lane < EE) {
    int run = offs_s[lane];
    for (int b = 0; b < NBLK; ++b) {
      bbase[b * EE + lane] = run;
      run += bhist[b * EE + lane];
    }
  }
}

// ---------------- scatter via LDS cursors into disjoint ranges ----------------
__global__ __launch_bounds__(256) void k_scatter(const int* __restrict__ eid,
                                                 const int* __restrict__ bbase,
                                                 int* __restrict__ idx) {
  __shared__ int cur[EE];
  if (threadIdx.x < EE) cur[threadIdx.x] = bbase[blockIdx.x * EE + threadIdx.x];
  __syncthreads();
  int t = blockIdx.x * 256 + threadIdx.x;
  int e = eid[t];
  int p = atomicAdd(&cur[e], 1);
  idx[p] = t;
}

// ---------------- weight transpose+cast: w[e][R][C] f32 -> wt[e][C][R] bf16 --------
__global__ __launch_bounds__(256) void k_transpose(
    const float* __restrict__ w, __bf16* __restrict__ wt, int R, int C)
{
  __shared__ float tile[32][33];
  int e = blockIdx.z;
  int c0 = blockIdx.x * 32, rb = blockIdx.y * 256;
  const float* we = w + (size_t)e * R * C;
  __bf16* wte = wt + (size_t)e * R * C;
  int tx = threadIdx.x & 31, ty = threadIdx.x >> 5;
  for (int s = 0; s < 8; ++s) {
    int r0 = rb + s * 32;
#pragma unroll
    for (int j = 0; j < 32; j += 8)
      tile[ty + j][tx] = we[(size_t)(r0 + ty + j) * C + (c0 + tx)];
    __syncthreads();
#pragma unroll
    for (int j = 0; j < 32; j += 8)
      wte[(size_t)(c0 + ty + j) * R + (r0 + tx)] = (__bf16)tile[tx][ty + j];
    __syncthreads();
  }
}

// ================= 8-phase 256x256 mainloop (T2+T3+T4+T5) =================
// LDS per operand: 4 half-tile slots of 16KB (256 rows x 32 cols bf16, 64B
// rows, XOR-swizzled chunks). Slot of (tile u, kk) = (2u+kk)&3 -> per-phase
// compile-time constants. Compute of iteration (u0=2t2,u1=u0+1) reads slots
// 0,0,1,1,2,2,3,3 at phases 1..8; stages write A/B halves of u1(kk1),
// u2(kk0), u2(kk1), u3(kk0) into slots 3,0,1,2 at phases 1/2,3/4,5/6,7/8 —
// each target region is dead >=1 barrier before the stage issues.
// vmcnt(8) at every even-phase end keeps 4 half-tiles (8 loads) in flight;
// each staged half has ~6 phases of latency cover. Last iteration peels
// with vmcnt 8 -> 4 -> 0.

#define STAGE_A(u, kk, slot) do { \
    gload_lds16(aSrc0 + (u) * 128 + (kk) * 64, sA + (slot) * 16384 + tid * 16); \
    gload_lds16(aSrc1 + (u) * 128 + (kk) * 64, sA + (slot) * 16384 + 8192 + tid * 16); \
  } while (0)
#define STAGE_B(u, kk, slot) do { \
    gload_lds16(bSrc0 + (u) * 128 + (kk) * 64, sB + (slot) * 16384 + tid * 16); \
    gload_lds16(bSrc1 + (u) * 128 + (kk) * 64, sB + (slot) * 16384 + 8192 + tid * 16); \
  } while (0)
#define LDA4(slot, mq) do { \
    const char* _b = sA + (slot) * 16384 + (mq) * 4096 + aoff; \
    af[0] = *(const bf16x8*)(_b); \
    af[1] = *(const bf16x8*)(_b + 1024); \
    af[2] = *(const bf16x8*)(_b + 2048); \
    af[3] = *(const bf16x8*)(_b + 3072); \
  } while (0)
#define LDB4(slot) do { \
    const char* _b = sB + (slot) * 16384 + boff; \
    bfr[0] = *(const bf16x8*)(_b); \
    bfr[1] = *(const bf16x8*)(_b + 1024); \
    bfr[2] = *(const bf16x8*)(_b + 2048); \
    bfr[3] = *(const bf16x8*)(_b + 3072); \
  } while (0)
#define MM16(mq) do { \
    __builtin_amdgcn_s_setprio(1); \
    _Pragma("unroll") \
    for (int _m = 0; _m < 4; ++_m) \
      _Pragma("unroll") \
      for (int _n = 0; _n < 4; ++_n) \
        acc[(mq) * 4 + _m][_n] = __builtin_amdgcn_mfma_f32_16x16x32_bf16( \
            af[_m], bfr[_n], acc[(mq) * 4 + _m][_n], 0, 0, 0); \
    __builtin_amdgcn_s_setprio(0); \
  } while (0)
#define BAR_IN()  do { __builtin_amdgcn_s_barrier(); __builtin_amdgcn_sched_barrier(0); } while (0)
#define BAR_OUT() do { __builtin_amdgcn_s_barrier(); } while (0)
#define VM8()  asm volatile("s_waitcnt vmcnt(8)" ::: "memory")
#define VM4()  asm volatile("s_waitcnt vmcnt(4)" ::: "memory")
#define VM0()  asm volatile("s_waitcnt vmcnt(0)" ::: "memory")

template <int NT>
__device__ __forceinline__ void moe_mainloop(
    const char* aSrc0, const char* aSrc1, const char* bSrc0, const char* bSrc1,
    char* sA, char* sB, int tid, int aoff, int boff, f32x4 (&acc)[8][4])
{
  bf16x8 af[4], bfr[4];

  // prologue: A0(0),B0(0),A1(0),B1(0),A0(1),B0(1) -> slots 0,0,1,1,2,2
  STAGE_A(0, 0, 0); STAGE_B(0, 0, 0);
  STAGE_A(0, 1, 1); STAGE_B(0, 1, 1);
  STAGE_A(1, 0, 2); STAGE_B(1, 0, 2);
  VM8();                 // first 2 halves (slot0 A+B) landed
  BAR_OUT();

  for (int t2 = 0; t2 < NT / 2 - 1; ++t2) {
    const int u1 = 2 * t2 + 1, u2 = 2 * t2 + 2, u3 = 2 * t2 + 3;
    // ph1 (kk0, mq0)
    LDA4(0, 0); LDB4(0);
    STAGE_A(u1, 1, 3);
    BAR_IN(); MM16(0); BAR_OUT();
    // ph2 (kk0, mq1)
    LDA4(0, 1);
    STAGE_B(u1, 1, 3);
    BAR_IN(); MM16(1); VM8(); BAR_OUT();
    // ph3 (kk1, mq0)
    LDA4(1, 0); LDB4(1);
    STAGE_A(u2, 0, 0);
    BAR_IN(); MM16(0); BAR_OUT();
    // ph4 (kk1, mq1)
    LDA4(1, 1);
    STAGE_B(u2, 0, 0);
    BAR_IN(); MM16(1); VM8(); BAR_OUT();
    // ph5 (tile u1, kk0, mq0)
    LDA4(2, 0); LDB4(2);
    STAGE_A(u2, 1, 1);
    BAR_IN(); MM16(0); BAR_OUT();
    // ph6
    LDA4(2, 1);
    STAGE_B(u2, 1, 1);
    BAR_IN(); MM16(1); VM8(); BAR_OUT();
    // ph7 (tile u1, kk1, mq0)
    LDA4(3, 0); LDB4(3);
    STAGE_A(u3, 0, 2);
    BAR_IN(); MM16(0); BAR_OUT();
    // ph8
    LDA4(3, 1);
    STAGE_B(u3, 0, 2);
    BAR_IN(); MM16(1); VM8(); BAR_OUT();
  }

  // peeled final iteration (tiles NT-2, NT-1): no u2/u3 stages
  {
    const int u1 = NT - 1;
    LDA4(0, 0); LDB4(0);
    STAGE_A(u1, 1, 3);
    BAR_IN(); MM16(0); BAR_OUT();
    LDA4(0, 1);
    STAGE_B(u1, 1, 3);
    BAR_IN(); MM16(1); VM8(); BAR_OUT();
    LDA4(1, 0); LDB4(1);
    BAR_IN(); MM16(0); BAR_OUT();
    LDA4(1, 1);
    BAR_IN(); MM16(1); VM4(); BAR_OUT();
    LDA4(2, 0); LDB4(2);
    BAR_IN(); MM16(0); BAR_OUT();
    LDA4(2, 1);
    BAR_IN(); MM16(1); VM0(); BAR_OUT();
    LDA4(3, 0); LDB4(3);
    BAR_IN(); MM16(0); BAR_OUT();
    LDA4(3, 1);
    BAR_IN(); MM16(1);
  }
}

// ---------------- GEMM 1: h = gelu(xbf_gather @ W1T[e]^T + b1) ----------------
__global__ __launch_bounds__(512, 2) void k_gemm1(
    const __bf16* __restrict__ xbf, const __bf16* __restrict__ w1t,
    const float* __restrict__ b1, const int* __restrict__ idx,
    const int* __restrict__ offs, const int2* __restrict__ tiles,
    __bf16* __restrict__ hbuf)
{
  int2 te = tiles[blockIdx.x];
  int e = te.x;
  if (e < 0) return;
  int mt = te.y, nt = blockIdx.y;
  int off = offs[e], cnt = offs[e + 1] - off;
  int n0 = nt * BN;

  __shared__ __align__(16) char smem[131072];
  char* sA = smem;
  char* sB = smem + 65536;

  const int tid = threadIdx.x;
  const int lane = tid & 63;
  const int wid = tid >> 6;
  const int wr = wid >> 2, wc = wid & 3;
  const int lr = lane & 15, lk = lane >> 4;
  const int xorb = ((lr >> 3) & 1) << 1;
  const int aoff = (wr * 128 + lr) * 64 + ((lk ^ xorb) * 16);
  const int boff = (wc * 64 + lr) * 64 + ((lk ^ xorb) * 16);

  // staging source addresses (rows fixed across K)
  int row0 = tid >> 2, row1 = (512 + tid) >> 2;
  int g0 = (tid & 3) ^ (((row0 >> 3) & 1) << 1);
  int g1 = ((512 + tid) & 3) ^ (((row1 >> 3) & 1) << 1);
  int rl0 = mt * BM + row0; if (rl0 >= cnt) rl0 = cnt - 1;
  int rl1 = mt * BM + row1; if (rl1 >= cnt) rl1 = cnt - 1;
  const char* aSrc0 = (const char*)xbf + (size_t)idx[off + rl0] * (DD * 2) + g0 * 16;
  const char* aSrc1 = (const char*)xbf + (size_t)idx[off + rl1] * (DD * 2) + g1 * 16;
  const char* bSrc0 = (const char*)w1t + ((size_t)e * HH + n0 + row0) * (DD * 2) + g0 * 16;
  const char* bSrc1 = (const char*)w1t + ((size_t)e * HH + n0 + row1) * (DD * 2) + g1 * 16;

  f32x4 acc[8][4] = {};
  moe_mainloop<DD / BK>(aSrc0, aSrc1, bSrc0, bSrc1, sA, sB, tid, aoff, boff, acc);

  // epilogue: bias + fast exact GELU -> bf16 h (compacted rows)
#pragma unroll
  for (int m = 0; m < 8; ++m) {
    int rb = mt * BM + wr * 128 + m * 16 + lk * 4;
#pragma unroll
    for (int n = 0; n < 4; ++n) {
      int col = n0 + wc * 64 + n * 16 + lr;
      float bias = b1[e * HH + col];
#pragma unroll
      for (int j = 0; j < 4; ++j) {
        int r = rb + j;
        if (r < cnt)
          hbuf[(size_t)(off + r) * HH + col] = (__bf16)fast_gelu(acc[m][n][j] + bias);
      }
    }
  }
}

// ---------------- GEMM 2: out = coef * (h @ W2T[e]^T + b2), scattered ----------------
__global__ __launch_bounds__(512, 2) void k_gemm2(
    const __bf16* __restrict__ hbuf, const __bf16* __restrict__ w2t,
    const float* __restrict__ b2, const int* __restrict__ idx,
    const int* __restrict__ offs, const int2* __restrict__ tiles,
    const float* __restrict__ coef, float* __restrict__ out)
{
  int2 te = tiles[blockIdx.x];
  int e = te.x;
  if (e < 0) return;
  int mt = te.y, nt = blockIdx.y;
  int off = offs[e], cnt = offs[e + 1] - off;
  int n0 = nt * BN;

  __shared__ __align__(16) char smem[131072];
  char* sA = smem;
  char* sB = smem + 65536;

  const int tid = threadIdx.x;
  const int lane = tid & 63;
  const int wid = tid >> 6;
  const int wr = wid >> 2, wc = wid & 3;
  const int lr = lane & 15, lk = lane >> 4;
  const int xorb = ((lr >> 3) & 1) << 1;
  const int aoff = (wr * 128 + lr) * 64 + ((lk ^ xorb) * 16);
  const int boff = (wc * 64 + lr) * 64 + ((lk ^ xorb) * 16);

  int row0 = tid >> 2, row1 = (512 + tid) >> 2;
  int g0 = (tid & 3) ^ (((row0 >> 3) & 1) << 1);
  int g1 = ((512 + tid) & 3) ^ (((row1 >> 3) & 1) << 1);
  int rl0 = mt * BM + row0; if (rl0 >= cnt) rl0 = cnt - 1;
  int rl1 = mt * BM + row1; if (rl1 >= cnt) rl1 = cnt - 1;
  const char* aSrc0 = (const char*)hbuf + (size_t)(off + rl0) * (HH * 2) + g0 * 16;
  const char* aSrc1 = (const char*)hbuf + (size_t)(off + rl1) * (HH * 2) + g1 * 16;
  const char* bSrc0 = (const char*)w2t + ((size_t)e * DD + n0 + row0) * (HH * 2) + g0 * 16;
  const char* bSrc1 = (const char*)w2t + ((size_t)e * DD + n0 + row1) * (HH * 2) + g1 * 16;

  f32x4 acc[8][4] = {};
  moe_mainloop<HH / BK>(aSrc0, aSrc1, bSrc0, bSrc1, sA, sB, tid, aoff, boff, acc);

  // epilogue: scale by coef, add b2, scatter rows to out (f32)
#pragma unroll
  for (int m = 0; m < 8; ++m) {
    int rb = mt * BM + wr * 128 + m * 16 + lk * 4;
#pragma unroll
    for (int j = 0; j < 4; ++j) {
      int r = rb + j;
      if (r < cnt) {
        int t = idx[off + r];
        float cf = coef[t];
#pragma unroll
        for (int n = 0; n < 4; ++n) {
          int col = n0 + wc * 64 + n * 16 + lr;
          out[(size_t)t * DD + col] = cf * (acc[m][n][j] + b2[e * DD + col]);
        }
      }
    }
  }
}

// ---------------- launch ----------------
extern "C" void kernel_launch(void* const* d_in, const int* in_sizes, int n_in,
                              void* d_out, int out_size, void* d_ws, size_t ws_size,
                              hipStream_t stream)
{
  const float* x  = (const float*)d_in[0];
  const float* W1 = (const float*)d_in[1];
  const float* b1 = (const float*)d_in[2];
  const float* W2 = (const float*)d_in[3];
  const float* b2 = (const float*)d_in[4];
  const float* Wg = (const float*)d_in[5];
  const float* bg = (const float*)d_in[6];
  float* out = (float*)d_out;

  char* ws = (char*)d_ws;
  size_t o = 0;
  int* offs   = (int*)(ws + o); o += 64;
  int2* tiles = (int2*)(ws + o); o += MAXT2 * 8;
  int* bhist  = (int*)(ws + o); o += NBLK * EE * 4;
  int* bbase  = (int*)(ws + o); o += NBLK * EE * 4;
  int* eid    = (int*)(ws + o); o += (size_t)NTOK * 4;
  float* coef = (float*)(ws + o); o += (size_t)NTOK * 4;
  int* idx    = (int*)(ws + o); o += (size_t)NTOK * 4;
  o = (o + 255) & ~(size_t)255;
  __bf16* xbf = (__bf16*)(ws + o); o += (size_t)NTOK * DD * 2;
  __bf16* w1t = (__bf16*)(ws + o); o += (size_t)EE * HH * DD * 2;
  __bf16* w2t = (__bf16*)(ws + o); o += (size_t)EE * DD * HH * 2;
  __bf16* hbuf = (__bf16*)(ws + o); o += (size_t)NTOK * HH * 2;

  k_gating<<<NTOK / 8, 256, 0, stream>>>(x, Wg, bg, eid, coef, xbf);
  k_hist<<<NBLK, 256, 0, stream>>>(eid, bhist);
  k_scan<<<1, 64, 0, stream>>>(bhist, offs, bbase, tiles);
  k_scatter<<<NBLK, 256, 0, stream>>>(eid, bbase, idx);
  k_transpose<<<dim3(HH / 32, DD / 256, EE), 256, 0, stream>>>(W1, w1t, DD, HH);
  k_transpose<<<dim3(DD / 32, HH / 256, EE), 256, 0, stream>>>(W2, w2t, HH, DD);
  k_gemm1<<<dim3(MAXT2, HH / BN), 512, 0, stream>>>(xbf, w1t, b1, idx, offs, tiles, hbuf);
  k_gemm2<<<dim3(MAXT2, DD / BN), 512, 0, stream>>>(hbuf, w2t, b2, idx, offs, tiles, coef, out);
}

// Round 8
// 862.562 us; speedup vs baseline: 1.0317x; 1.0317x over previous
//
#include <hip/hip_runtime.h>
#include <hip/hip_bf16.h>
#include <math.h>

#define NTOK 32768
#define DD   1024
#define HH   2048
#define EE   8

#define BM 256
#define BN 256
#define BK 64
#define MAXT2 144  // max 256-row tiles: 128 + 7 worst-case, padded
#define NBLK 128   // NTOK / 256

typedef __bf16 bf16x8 __attribute__((ext_vector_type(8)));
typedef __bf16 bf16x4 __attribute__((ext_vector_type(4)));
typedef float  f32x4  __attribute__((ext_vector_type(4)));

__device__ __forceinline__ void gload_lds16(const void* g, void* l) {
  __builtin_amdgcn_global_load_lds((__attribute__((address_space(1))) void*)(g),
                                   (__attribute__((address_space(3))) void*)(l),
                                   16, 0, 0);
}

__device__ __forceinline__ float fast_gelu(float v) {
  // exact-GELU via A&S 7.1.26 erf (|err| <= 1.5e-7)
  float az = fabsf(v) * 0.70710678118654752f;
  float t = 1.0f / (1.0f + 0.3275911f * az);
  float poly = t * (0.254829592f + t * (-0.284496736f +
               t * (1.421413741f + t * (-1.453152027f + t * 1.061405429f))));
  float erfa = 1.0f - poly * __expf(-az * az);
  float s = copysignf(erfa, v);
  return 0.5f * v * (1.0f + s);
}

// ---------------- gating + fused x->bf16 cast ----------------
__global__ __launch_bounds__(256) void k_gating(
    const float* __restrict__ x, const float* __restrict__ wg,
    const float* __restrict__ bg, int* __restrict__ eid,
    float* __restrict__ coef, __bf16* __restrict__ xbf)
{
  int lane = threadIdx.x & 63;
  int wave = threadIdx.x >> 6;
  int t0 = blockIdx.x * 8 + wave * 2;

  const float* xr0 = x + (size_t)t0 * DD;
  const float* xr1 = x + (size_t)(t0 + 1) * DD;
  double s0[8] = {}, s1[8] = {};
#pragma unroll
  for (int it = 0; it < 4; ++it) {
    int c0 = it * 256 + lane * 4;
    float4 xa = *(const float4*)(xr0 + c0);
    float4 xb = *(const float4*)(xr1 + c0);
    bf16x4 ca, cb;
#pragma unroll
    for (int j = 0; j < 4; ++j) { ca[j] = (__bf16)(&xa.x)[j]; cb[j] = (__bf16)(&xb.x)[j]; }
    *(bf16x4*)(xbf + (size_t)t0 * DD + c0) = ca;
    *(bf16x4*)(xbf + (size_t)(t0 + 1) * DD + c0) = cb;
    const float* w = wg + (size_t)c0 * EE;
#pragma unroll
    for (int j = 0; j < 4; ++j) {
      double fa = (double)(&xa.x)[j];
      double fb = (double)(&xb.x)[j];
#pragma unroll
      for (int e2 = 0; e2 < 8; ++e2) {
        double wv = (double)w[j * EE + e2];
        s0[e2] += fa * wv;
        s1[e2] += fb * wv;
      }
    }
  }

  int sel = lane & 1, sel2 = (lane >> 1) & 1, sel3 = (lane >> 2) & 1;
  int e = (lane & 1) * 4 + (lane & 2) + ((lane >> 2) & 1);
  double bge = (double)bg[e];

#pragma unroll
  for (int tk = 0; tk < 2; ++tk) {
    double* s = tk ? s1 : s0;
    double v4[4];
#pragma unroll
    for (int j = 0; j < 4; ++j) {
      double keep = sel ? s[4 + j] : s[j];
      double send = sel ? s[j] : s[4 + j];
      v4[j] = keep + __shfl_xor(send, 1, 64);
    }
    double v2[2];
#pragma unroll
    for (int j = 0; j < 2; ++j) {
      double keep = sel2 ? v4[2 + j] : v4[j];
      double send = sel2 ? v4[j] : v4[2 + j];
      v2[j] = keep + __shfl_xor(send, 2, 64);
    }
    double keep = sel3 ? v2[1] : v2[0];
    double send = sel3 ? v2[0] : v2[1];
    double tt = keep + __shfl_xor(send, 4, 64);
    tt += __shfl_xor(tt, 8, 64);
    tt += __shfl_xor(tt, 16, 64);
    tt += __shfl_xor(tt, 32, 64);
    double logit = tt + bge;
    double ml = logit; int me = e;
#pragma unroll
    for (int d2 = 1; d2 < 8; d2 <<= 1) {
      double ol = __shfl_xor(ml, d2, 64);
      int oe = __shfl_xor(me, d2, 64);
      if (ol > ml || (ol == ml && oe < me)) { ml = ol; me = oe; }
    }
    double se = exp(logit - ml);
#pragma unroll
    for (int d2 = 1; d2 < 8; d2 <<= 1) se += __shfl_xor(se, d2, 64);
    if (lane == 0) {
      eid[t0 + tk] = me;
      coef[t0 + tk] = (float)(1.0 / se);
    }
  }
}

// ---------------- per-block histogram (LDS atomics only) ----------------
__global__ __launch_bounds__(256) void k_hist(const int* __restrict__ eid,
                                              int* __restrict__ bhist) {
  __shared__ int h[EE];
  if (threadIdx.x < EE) h[threadIdx.x] = 0;
  __syncthreads();
  int t = blockIdx.x * 256 + threadIdx.x;
  atomicAdd(&h[eid[t]], 1);
  __syncthreads();
  if (threadIdx.x < EE) bhist[blockIdx.x * EE + threadIdx.x] = h[threadIdx.x];
}

// ---------------- scan: offs, per-block bases, 256-tile table ----------------
__global__ void k_scan(const int* __restrict__ bhist, int* __restrict__ offs,
                       int* __restrict__ bbase, int2* __restrict__ tiles) {
  __shared__ int counts_s[EE];
  __shared__ int offs_s[EE + 1];
  int lane = threadIdx.x;
  if (lane < EE) {
    int sum = 0;
    for (int b = 0; b < NBLK; ++b) sum += bhist[b * EE + lane];
    counts_s[lane] = sum;
  }
  __syncthreads();
  if (lane == 0) {
    int a = 0;
    for (int e = 0; e < EE; ++e) { offs_s[e] = a; offs[e] = a; a += counts_s[e]; }
    offs_s[EE] = a; offs[EE] = a;
    int nt = 0;
    for (int e = 0; e < EE; ++e)
      for (int mt = 0; mt * BM < counts_s[e]; ++mt) tiles[nt++] = make_int2(e, mt);
    for (; nt < MAXT2; ++nt) tiles[nt] = make_int2(-1, 0);
  }
  __syncthreads();
  if (lane < EE) {
    int run = offs_s[lane];
    for (int b = 0; b < NBLK; ++b) {
      bbase[b * EE + lane] = run;
      run += bhist[b * EE + lane];
    }
  }
}

// ---------------- scatter via LDS cursors into disjoint ranges ----------------
__global__ __launch_bounds__(256) void k_scatter(const int* __restrict__ eid,
                                                 const int* __restrict__ bbase,
                                                 int* __restrict__ idx) {
  __shared__ int cur[EE];
  if (threadIdx.x < EE) cur[threadIdx.x] = bbase[blockIdx.x * EE + threadIdx.x];
  __syncthreads();
  int t = blockIdx.x * 256 + threadIdx.x;
  int e = eid[t];
  int p = atomicAdd(&cur[e], 1);
  idx[p] = t;
}

// ---------------- weight transpose+cast: w[e][R][C] f32 -> wt[e][C][R] bf16 --------
__global__ __launch_bounds__(256) void k_transpose(
    const float* __restrict__ w, __bf16* __restrict__ wt, int R, int C)
{
  __shared__ float tile[32][33];
  int e = blockIdx.z;
  int c0 = blockIdx.x * 32, rb = blockIdx.y * 256;
  const float* we = w + (size_t)e * R * C;
  __bf16* wte = wt + (size_t)e * R * C;
  int tx = threadIdx.x & 31, ty = threadIdx.x >> 5;
  for (int s = 0; s < 8; ++s) {
    int r0 = rb + s * 32;
#pragma unroll
    for (int j = 0; j < 32; j += 8)
      tile[ty + j][tx] = we[(size_t)(r0 + ty + j) * C + (c0 + tx)];
    __syncthreads();
#pragma unroll
    for (int j = 0; j < 32; j += 8)
      wte[(size_t)(c0 + ty + j) * R + (r0 + tx)] = (__bf16)tile[tx][ty + j];
    __syncthreads();
  }
}

// ================= 256x256 mainloop, 128B-granule staging =================
// LDS: A dbuf 2x32KB + B dbuf 2x32KB. Buffer = [256 rows][128B] (full BK=64
// K-slice per row), rows staged 8 thr x 16B = 128B bursts. XOR chunk swizzle:
// LDS(row,ch) = G(row, ch^(row&7)), applied on both stage-source and read.
// Per K-tile u (4 phases): ph1 stages G1(u+1)={A rows 0-63,128-191; B all} (6
// gloads), ph2 stages G2(u+1)={A rows 64-127,192-255} (2 gloads). Waits:
// vmcnt(6) at ph1-end (drains G2(u)), vmcnt(2) at ph4-end (drains G1(u+1)).
// 3-phase latency slack on every staged load; never drains to 0 mid-loop.

#define STG(p, db, i, ko) \
  gload_lds16((p) + (ko), (db) + (((i) * 512 + tid) * 16))
#define STAGE_G1(nxt, ko) do { \
    char* dA = sA + (nxt) * 32768; char* dB = sB + (nxt) * 32768; \
    STG(aRB0, dA, 0, ko); STG(aRB2, dA, 2, ko); \
    STG(bRB0, dB, 0, ko); STG(bRB1, dB, 1, ko); \
    STG(bRB2, dB, 2, ko); STG(bRB3, dB, 3, ko); \
  } while (0)
#define STAGE_G2(nxt, ko) do { \
    char* dA = sA + (nxt) * 32768; \
    STG(aRB1, dA, 1, ko); STG(aRB3, dA, 3, ko); \
  } while (0)
#define LDA4(cur, mq, aoffk) do { \
    const char* _b = sA + (cur) * 32768 + (mq) * 8192 + (aoffk); \
    af[0] = *(const bf16x8*)(_b); \
    af[1] = *(const bf16x8*)(_b + 2048); \
    af[2] = *(const bf16x8*)(_b + 4096); \
    af[3] = *(const bf16x8*)(_b + 6144); \
  } while (0)
#define LDB4(cur, boffk) do { \
    const char* _b = sB + (cur) * 32768 + (boffk); \
    bfr[0] = *(const bf16x8*)(_b); \
    bfr[1] = *(const bf16x8*)(_b + 2048); \
    bfr[2] = *(const bf16x8*)(_b + 4096); \
    bfr[3] = *(const bf16x8*)(_b + 6144); \
  } while (0)
#define MM16(mq) do { \
    __builtin_amdgcn_s_setprio(1); \
    _Pragma("unroll") \
    for (int _m = 0; _m < 4; ++_m) \
      _Pragma("unroll") \
      for (int _n = 0; _n < 4; ++_n) \
        acc[(mq) * 4 + _m][_n] = __builtin_amdgcn_mfma_f32_16x16x32_bf16( \
            af[_m], bfr[_n], acc[(mq) * 4 + _m][_n], 0, 0, 0); \
    __builtin_amdgcn_s_setprio(0); \
  } while (0)
#define BAR_IN()  do { __builtin_amdgcn_s_barrier(); __builtin_amdgcn_sched_barrier(0); } while (0)
#define BAR_OUT() do { __builtin_amdgcn_s_barrier(); } while (0)
#define VM6()  asm volatile("s_waitcnt vmcnt(6)" ::: "memory")
#define VM2()  asm volatile("s_waitcnt vmcnt(2)" ::: "memory")
#define VM0()  asm volatile("s_waitcnt vmcnt(0)" ::: "memory")

template <int NT>
__device__ __forceinline__ void moe_mainloop(
    const char* aRB0, const char* aRB1, const char* aRB2, const char* aRB3,
    const char* bRB0, const char* bRB1, const char* bRB2, const char* bRB3,
    char* sA, char* sB, int tid,
    int aoff0, int aoff1, int boff0, int boff1, f32x4 (&acc)[8][4])
{
  bf16x8 af[4], bfr[4];

  // prologue: tile 0 -> buf 0
  STAGE_G1(0, 0);
  STAGE_G2(0, 0);
  VM2();               // G1(0) landed
  BAR_OUT();

  int cur = 0;
  for (int u = 0; u < NT - 1; ++u) {
    int nxt = cur ^ 1;
    int ko = (u + 1) * 128;
    // ph1: kk0 mq0
    STAGE_G1(nxt, ko);
    LDA4(cur, 0, aoff0); LDB4(cur, boff0);
    BAR_IN(); MM16(0); VM6(); BAR_OUT();
    // ph2: kk0 mq1
    STAGE_G2(nxt, ko);
    LDA4(cur, 1, aoff0);
    BAR_IN(); MM16(1); BAR_OUT();
    // ph3: kk1 mq0
    LDA4(cur, 0, aoff1); LDB4(cur, boff1);
    BAR_IN(); MM16(0); BAR_OUT();
    // ph4: kk1 mq1
    LDA4(cur, 1, aoff1);
    BAR_IN(); MM16(1); VM2(); BAR_OUT();
    cur = nxt;
  }
  // peel: tile NT-1, no staging
  LDA4(cur, 0, aoff0); LDB4(cur, boff0);
  BAR_IN(); MM16(0); VM0(); BAR_OUT();
  LDA4(cur, 1, aoff0);
  BAR_IN(); MM16(1); BAR_OUT();
  LDA4(cur, 0, aoff1); LDB4(cur, boff1);
  BAR_IN(); MM16(0); BAR_OUT();
  LDA4(cur, 1, aoff1);
  BAR_IN(); MM16(1);
}

// ---------------- GEMM 1: h = gelu(xbf_gather @ W1T[e]^T + b1) ----------------
__global__ __launch_bounds__(512, 2) void k_gemm1(
    const __bf16* __restrict__ xbf, const __bf16* __restrict__ w1t,
    const float* __restrict__ b1, const int* __restrict__ idx,
    const int* __restrict__ offs, const int2* __restrict__ tiles,
    __bf16* __restrict__ hbuf)
{
  // bijective XCD swizzle: XCD c owns N-column c for all experts (W-panel 4MB in its L2)
  int bid = blockIdx.x + 144 * blockIdx.y;     // grid (144, 8) -> 1152
  int bid2 = (bid & 7) * 144 + (bid >> 3);
  int xt = bid2 % 144;
  int yt = bid2 / 144;

  int2 te = tiles[xt];
  int e = te.x;
  if (e < 0) return;
  int mt = te.y;
  int off = offs[e], cnt = offs[e + 1] - off;
  int n0 = yt * BN;

  __shared__ __align__(16) char smem[131072];
  char* sA = smem;
  char* sB = smem + 65536;

  const int tid = threadIdx.x;
  const int lane = tid & 63;
  const int wid = tid >> 6;
  const int wr = wid >> 2, wc = wid & 3;
  const int lr = lane & 15, lk = lane >> 4;
  const int ch0 = ((lk) ^ (lr & 7)) * 16;
  const int ch1 = ((4 + lk) ^ (lr & 7)) * 16;
  const int aoff0 = (wr * 128 + lr) * 128 + ch0;
  const int aoff1 = (wr * 128 + lr) * 128 + ch1;
  const int boff0 = (wc * 64 + lr) * 128 + ch0;
  const int boff1 = (wc * 64 + lr) * 128 + ch1;

  // staging sources: 8 thr/row, 128B per row
  const int srow = tid >> 3;                       // 0..63
  const int chsw = ((tid & 7) ^ (srow & 7)) * 16;  // both-sides XOR swizzle
  const char* aRB[4];
  const char* bRB[4];
#pragma unroll
  for (int i = 0; i < 4; ++i) {
    int r = i * 64 + srow;
    int rl = mt * BM + r; if (rl >= cnt) rl = cnt - 1;
    aRB[i] = (const char*)xbf + (size_t)idx[off + rl] * (DD * 2) + chsw;
    bRB[i] = (const char*)w1t + ((size_t)e * HH + n0 + r) * (DD * 2) + chsw;
  }

  f32x4 acc[8][4] = {};
  moe_mainloop<DD / BK>(aRB[0], aRB[1], aRB[2], aRB[3],
                        bRB[0], bRB[1], bRB[2], bRB[3],
                        sA, sB, tid, aoff0, aoff1, boff0, boff1, acc);

  // ---- epilogue: GELU + LDS repack -> coalesced 128B bf16 row stores ----
  __syncthreads();
  char* wreg = smem + wid * 16384;   // [128 rows][64 cols] bf16
  float bias[4];
#pragma unroll
  for (int n = 0; n < 4; ++n) bias[n] = b1[e * HH + n0 + wc * 64 + n * 16 + lr];
#pragma unroll
  for (int mq = 0; mq < 2; ++mq)
#pragma unroll
    for (int mm = 0; mm < 4; ++mm)
#pragma unroll
      for (int n = 0; n < 4; ++n)
#pragma unroll
        for (int j = 0; j < 4; ++j) {
          int lrow = mq * 64 + mm * 16 + lk * 4 + j;
          *(__bf16*)(wreg + (lrow * 64 + n * 16 + lr) * 2) =
              (__bf16)fast_gelu(acc[mq * 4 + mm][n][j] + bias[n]);
        }
  asm volatile("s_waitcnt lgkmcnt(0)" ::: "memory");
  int gcol = n0 + wc * 64 + (lane & 7) * 8;
  int rowb = mt * BM + wr * 128 + (lane >> 3);
#pragma unroll
  for (int it = 0; it < 16; ++it) {
    bf16x8 v = *(bf16x8*)(wreg + it * 1024 + lane * 16);
    int grow = rowb + it * 8;
    if (grow < cnt)
      *(bf16x8*)((char*)hbuf + ((size_t)(off + grow) * HH + gcol) * 2) = v;
  }
}

// ---------------- GEMM 2: out = coef * (h @ W2T[e]^T + b2), scattered ----------------
__global__ __launch_bounds__(512, 2) void k_gemm2(
    const __bf16* __restrict__ hbuf, const __bf16* __restrict__ w2t,
    const float* __restrict__ b2, const int* __restrict__ idx,
    const int* __restrict__ offs, const int2* __restrict__ tiles,
    const float* __restrict__ coef, float* __restrict__ out)
{
  int bid = blockIdx.x + 144 * blockIdx.y;     // grid (144, 4) -> 576
  int bid2 = (bid & 7) * 72 + (bid >> 3);
  int xt = bid2 % 144;
  int yt = bid2 / 144;

  int2 te = tiles[xt];
  int e = te.x;
  if (e < 0) return;
  int mt = te.y;
  int off = offs[e], cnt = offs[e + 1] - off;
  int n0 = yt * BN;

  __shared__ __align__(16) char smem[131072];
  char* sA = smem;
  char* sB = smem + 65536;

  const int tid = threadIdx.x;
  const int lane = tid & 63;
  const int wid = tid >> 6;
  const int wr = wid >> 2, wc = wid & 3;
  const int lr = lane & 15, lk = lane >> 4;
  const int ch0 = ((lk) ^ (lr & 7)) * 16;
  const int ch1 = ((4 + lk) ^ (lr & 7)) * 16;
  const int aoff0 = (wr * 128 + lr) * 128 + ch0;
  const int aoff1 = (wr * 128 + lr) * 128 + ch1;
  const int boff0 = (wc * 64 + lr) * 128 + ch0;
  const int boff1 = (wc * 64 + lr) * 128 + ch1;

  const int srow = tid >> 3;
  const int chsw = ((tid & 7) ^ (srow & 7)) * 16;
  const char* aRB[4];
  const char* bRB[4];
#pragma unroll
  for (int i = 0; i < 4; ++i) {
    int r = i * 64 + srow;
    int rl = mt * BM + r; if (rl >= cnt) rl = cnt - 1;
    aRB[i] = (const char*)hbuf + (size_t)(off + rl) * (HH * 2) + chsw;
    bRB[i] = (const char*)w2t + ((size_t)e * DD + n0 + r) * (HH * 2) + chsw;
  }

  f32x4 acc[8][4] = {};
  moe_mainloop<HH / BK>(aRB[0], aRB[1], aRB[2], aRB[3],
                        bRB[0], bRB[1], bRB[2], bRB[3],
                        sA, sB, tid, aoff0, aoff1, boff0, boff1, acc);

  // ---- epilogue: LDS repack (f32, 2 passes) -> coalesced 256B row stores ----
  __syncthreads();
  char* wreg = smem + wid * 16384;   // [64 rows][64 cols] f32 per pass
  float b2v[4];
#pragma unroll
  for (int n = 0; n < 4; ++n) b2v[n] = b2[e * DD + n0 + wc * 64 + n * 16 + lr];
  int gcol = n0 + wc * 64 + (lane & 15) * 4;
#pragma unroll
  for (int pass = 0; pass < 2; ++pass) {
    if (pass) asm volatile("s_waitcnt lgkmcnt(0)" ::: "memory");
#pragma unroll
    for (int mm = 0; mm < 4; ++mm)
#pragma unroll
      for (int n = 0; n < 4; ++n)
#pragma unroll
        for (int j = 0; j < 4; ++j) {
          int lrow = mm * 16 + lk * 4 + j;
          *(float*)(wreg + (lrow * 64 + n * 16 + lr) * 4) =
              acc[pass * 4 + mm][n][j] + b2v[n];
        }
    asm volatile("s_waitcnt lgkmcnt(0)" ::: "memory");
#pragma unroll
    for (int it = 0; it < 16; ++it) {
      float4 v = *(float4*)(wreg + it * 1024 + lane * 16);
      int grow = mt * BM + wr * 128 + pass * 64 + it * 4 + (lane >> 4);
      if (grow < cnt) {
        int t = idx[off + grow];
        float cf = coef[t];
        float4 o;
        o.x = v.x * cf; o.y = v.y * cf; o.z = v.z * cf; o.w = v.w * cf;
        *(float4*)(out + (size_t)t * DD + gcol) = o;
      }
    }
  }
}

// ---------------- launch ----------------
extern "C" void kernel_launch(void* const* d_in, const int* in_sizes, int n_in,
                              void* d_out, int out_size, void* d_ws, size_t ws_size,
                              hipStream_t stream)
{
  const float* x  = (const float*)d_in[0];
  const float* W1 = (const float*)d_in[1];
  const float* b1 = (const float*)d_in[2];
  const float* W2 = (const float*)d_in[3];
  const float* b2 = (const float*)d_in[4];
  const float* Wg = (const float*)d_in[5];
  const float* bg = (const float*)d_in[6];
  float* out = (float*)d_out;

  char* ws = (char*)d_ws;
  size_t o = 0;
  int* offs   = (int*)(ws + o); o += 64;
  int2* tiles = (int2*)(ws + o); o += MAXT2 * 8;
  int* bhist  = (int*)(ws + o); o += NBLK * EE * 4;
  int* bbase  = (int*)(ws + o); o += NBLK * EE * 4;
  int* eid    = (int*)(ws + o); o += (size_t)NTOK * 4;
  float* coef = (float*)(ws + o); o += (size_t)NTOK * 4;
  int* idx    = (int*)(ws + o); o += (size_t)NTOK * 4;
  o = (o + 255) & ~(size_t)255;
  __bf16* xbf = (__bf16*)(ws + o); o += (size_t)NTOK * DD * 2;
  __bf16* w1t = (__bf16*)(ws + o); o += (size_t)EE * HH * DD * 2;
  __bf16* w2t = (__bf16*)(ws + o); o += (size_t)EE * DD * HH * 2;
  __bf16* hbuf = (__bf16*)(ws + o); o += (size_t)NTOK * HH * 2;

  k_gating<<<NTOK / 8, 256, 0, stream>>>(x, Wg, bg, eid, coef, xbf);
  k_hist<<<NBLK, 256, 0, stream>>>(eid, bhist);
  k_scan<<<1, 64, 0, stream>>>(bhist, offs, bbase, tiles);
  k_scatter<<<NBLK, 256, 0, stream>>>(eid, bbase, idx);
  k_transpose<<<dim3(HH / 32, DD / 256, EE), 256, 0, stream>>>(W1, w1t, DD, HH);
  k_transpose<<<dim3(DD / 32, HH / 256, EE), 256, 0, stream>>>(W2, w2t, HH, DD);
  k_gemm1<<<dim3(MAXT2, HH / BN), 512, 0, stream>>>(xbf, w1t, b1, idx, offs, tiles, hbuf);
  k_gemm2<<<dim3(MAXT2, DD / BN), 512, 0, stream>>>(hbuf, w2t, b2, idx, offs, tiles, coef, out);
}